// Round 5
// baseline (49.750 us; speedup 1.0000x reference)
//
#include <hip/hip_runtime.h>
#include <math.h>

#define VOCAB  30522
#define HIDDEN 768
#define EMB    128
#define BATCH  1024
#define QLEN   32
#define DLEN   180
#define NEGV   (-1e4f)

typedef __attribute__((ext_vector_type(8))) short bf16x8;
typedef __attribute__((ext_vector_type(4))) float f32x4;

__device__ __forceinline__ unsigned short f2bf(float x) {
  union { float f; unsigned u; } v; v.f = x;
  unsigned r = v.u + 0x7FFFu + ((v.u >> 16) & 1u);
  return (unsigned short)(r >> 16);
}
__device__ __forceinline__ float bf2f(unsigned short h) {
  union { float f; unsigned u; } v; v.u = ((unsigned)h) << 16;
  return v.f;
}
// split 2 fp32 -> packed bf16 hi pair + packed bf16 lo pair
__device__ __forceinline__ void split_pk(float x0, float x1, unsigned& h, unsigned& l) {
  asm("v_cvt_pk_bf16_f32 %0, %1, %2" : "=v"(h) : "v"(x0), "v"(x1));
  float h0, h1;
  h0 = __uint_as_float(h << 16);
  h1 = __uint_as_float(h & 0xffff0000u);
  float l0 = x0 - h0, l1 = x1 - h1;
  asm("v_cvt_pk_bf16_f32 %0, %1, %2" : "=v"(l) : "v"(l0), "v"(l1));
}

// ---------------------------------------------------------------------------
// Kernel 0: W [768][128] fp32 -> fragment-major bf16 hi/lo tables.
// wf[(kkg*8 + nt)*64 + lane][j] holds W[kkg*32 + (lane>>4)*8 + j][nt*16 + (lane&15)]
// = exactly the 16x16x32 B-fragment each lane needs: one 16B load/lane.
// ---------------------------------------------------------------------------
__global__ __launch_bounds__(256) void prep_wfrag(
    const float* __restrict__ W, unsigned short* __restrict__ wfh,
    unsigned short* __restrict__ wfl) {
  int g = blockIdx.x * 256 + threadIdx.x;   // 0..12287
  if (g >= 24 * 8 * 64) return;
  int lane = g & 63, nt = (g >> 6) & 7, kk = g >> 9;
  int lr = lane & 15, kq = lane >> 4;
  int n = nt * 16 + lr;
  int k0 = kk * 32 + kq * 8;
  unsigned short hh[8], ll[8];
#pragma unroll
  for (int j = 0; j < 8; ++j) {
    float x = W[(size_t)(k0 + j) * EMB + n];
    unsigned short hi = f2bf(x);
    hh[j] = hi;
    ll[j] = f2bf(x - bf2f(hi));
  }
  size_t base = (size_t)g * 8;
#pragma unroll
  for (int j = 0; j < 2; ++j) {
    *(ushort4*)(wfh + base + j * 4) = *(ushort4*)(hh + j * 4);
    *(ushort4*)(wfl + base + j * 4) = *(ushort4*)(ll + j * 4);
  }
}

// ---------------------------------------------------------------------------
// Kernel 1: pebf[v] = bf16(normalize(emb[v] @ W + b)), bf16x3-split MFMA.
// 954 blocks x 32 rows; 4 waves, each n-strip of 32 cols (wave tile 32x32).
// K in 6 chunks of BK=128. Per chunk: [all 16 B-frag loads (L2)] then
// [A prefetch (HBM)] (sched_barrier pins order; in-order vmcnt means B-waits
// never chain behind HBM), MFMAs, split->ds_write next buf, ONE barrier.
// ---------------------------------------------------------------------------
__global__ __launch_bounds__(256) void colbert_proj_mfma(
    const float* __restrict__ emb, const unsigned short* __restrict__ wfh,
    const unsigned short* __restrict__ wfl, const float* __restrict__ bias,
    unsigned short* __restrict__ pebf) {
  __shared__ __align__(16) char smem[32768];  // 2 bufs x (Ah 8K + Al 8K)

  const int tid  = threadIdx.x;
  const int lane = tid & 63;
  const int wid  = tid >> 6;   // wave = n-strip (cols wid*32..+31)
  const int lr   = lane & 15;
  const int kq   = lane >> 4;
  const int row0 = blockIdx.x * 32;

  f32x4 acc[2][2];
#pragma unroll
  for (int mi = 0; mi < 2; ++mi)
#pragma unroll
    for (int ni = 0; ni < 2; ++ni) acc[mi][ni] = (f32x4)0.f;

  float4 ar[4];
  // prologue: load chunk 0 (32 rows x 128 cols fp32; 512B segments/wave-instr)
#pragma unroll
  for (int i = 0; i < 4; ++i) {
    int idx = i * 256 + tid;
    int row = idx >> 5, c4 = idx & 31;
    int gr = row0 + row; if (gr > VOCAB - 1) gr = VOCAB - 1;
    ar[i] = *(const float4*)(emb + (size_t)gr * HIDDEN + c4 * 4);
  }

#define WRITE_A(bufidx)                                                        \
  {                                                                            \
    char* Ahb = smem + (bufidx) * 16384;                                       \
    char* Alb = Ahb + 8192;                                                    \
    _Pragma("unroll")                                                          \
    for (int i = 0; i < 4; ++i) {                                              \
      int idx = i * 256 + tid;                                                 \
      int row = idx >> 5, c4 = idx & 31;                                       \
      unsigned h0, l0, h1, l1;                                                 \
      split_pk(ar[i].x, ar[i].y, h0, l0);                                      \
      split_pk(ar[i].z, ar[i].w, h1, l1);                                      \
      int byt = (row * 256 + c4 * 8) ^ ((row & 7) << 4);                       \
      *(uint2*)(Ahb + byt) = make_uint2(h0, h1);                               \
      *(uint2*)(Alb + byt) = make_uint2(l0, l1);                               \
    }                                                                          \
  }

  WRITE_A(0);
  __syncthreads();

  for (int hc = 0; hc < 6; ++hc) {
    const int cur = hc & 1;
    // --- B fragments for the whole chunk, issued FIRST (L2-resident) ---
    bf16x8 bh[4][2], bl[4][2];
#pragma unroll
    for (int kk = 0; kk < 4; ++kk)
#pragma unroll
      for (int ni = 0; ni < 2; ++ni) {
        size_t g = ((size_t)((hc * 4 + kk) * 8 + wid * 2 + ni) * 64 + lane) * 8;
        bh[kk][ni] = *(const bf16x8*)(wfh + g);
        bl[kk][ni] = *(const bf16x8*)(wfl + g);
      }
    __builtin_amdgcn_sched_barrier(0);  // pin: A (HBM) issues after B (L2)
    // --- A prefetch for next chunk (HBM latency hides under MFMA phase) ---
    if (hc < 5) {
#pragma unroll
      for (int i = 0; i < 4; ++i) {
        int idx = i * 256 + tid;
        int row = idx >> 5, c4 = idx & 31;
        int gr = row0 + row; if (gr > VOCAB - 1) gr = VOCAB - 1;
        ar[i] = *(const float4*)(emb + (size_t)gr * HIDDEN + (hc + 1) * 128 + c4 * 4);
      }
    }
    char* Ahb = smem + cur * 16384;
    char* Alb = Ahb + 8192;
#pragma unroll
    for (int kk = 0; kk < 4; ++kk) {
      bf16x8 ah[2], al[2];
#pragma unroll
      for (int mi = 0; mi < 2; ++mi) {
        int row = mi * 16 + lr;
        int byt = (row * 256 + kk * 64 + kq * 16) ^ ((row & 7) << 4);
        ah[mi] = *(bf16x8*)(Ahb + byt);
        al[mi] = *(bf16x8*)(Alb + byt);
      }
#pragma unroll
      for (int mi = 0; mi < 2; ++mi)
#pragma unroll
        for (int ni = 0; ni < 2; ++ni) {
          acc[mi][ni] = __builtin_amdgcn_mfma_f32_16x16x32_bf16(ah[mi], bh[kk][ni], acc[mi][ni], 0, 0, 0);
          acc[mi][ni] = __builtin_amdgcn_mfma_f32_16x16x32_bf16(ah[mi], bl[kk][ni], acc[mi][ni], 0, 0, 0);
          acc[mi][ni] = __builtin_amdgcn_mfma_f32_16x16x32_bf16(al[mi], bh[kk][ni], acc[mi][ni], 0, 0, 0);
        }
    }
    if (hc < 5) WRITE_A(cur ^ 1);
    __syncthreads();
  }

  // epilogue: bias + L2-normalize -> bf16. Reuse LDS as fp32 [32][132].
  float* ep = (float*)smem;
#pragma unroll
  for (int ni = 0; ni < 2; ++ni) {
    int col = wid * 32 + ni * 16 + lr;
    float bb = bias[col];
#pragma unroll
    for (int mi = 0; mi < 2; ++mi)
#pragma unroll
      for (int j = 0; j < 4; ++j) {
        int r = mi * 16 + kq * 4 + j;   // C: col=lane&15, row=(lane>>4)*4+j
        ep[r * 132 + col] = acc[mi][ni][j] + bb;
      }
  }
  __syncthreads();
  {
    int row = tid >> 3, oct = tid & 7;   // 8 threads per row, 16 cols each
    float4 vv[4];
    float ss = 0.f;
#pragma unroll
    for (int i = 0; i < 4; ++i) {
      vv[i] = *(float4*)&ep[row * 132 + oct * 16 + i * 4];
      ss += vv[i].x * vv[i].x + vv[i].y * vv[i].y + vv[i].z * vv[i].z + vv[i].w * vv[i].w;
    }
    ss += __shfl_xor(ss, 1);
    ss += __shfl_xor(ss, 2);
    ss += __shfl_xor(ss, 4);
    float sc = 1.f / (sqrtf(ss) + 1e-12f);
    int gr = row0 + row;
    if (gr < VOCAB) {
      unsigned pk[8];
#pragma unroll
      for (int i = 0; i < 4; ++i) {
        pk[i * 2 + 0] = (unsigned)f2bf(vv[i].x * sc) | ((unsigned)f2bf(vv[i].y * sc) << 16);
        pk[i * 2 + 1] = (unsigned)f2bf(vv[i].z * sc) | ((unsigned)f2bf(vv[i].w * sc) << 16);
      }
      uint4* dst = (uint4*)(pebf + (size_t)gr * EMB + oct * 16);
      dst[0] = make_uint4(pk[0], pk[1], pk[2], pk[3]);
      dst[1] = make_uint4(pk[4], pk[5], pk[6], pk[7]);
    }
  }
}

// ---------------------------------------------------------------------------
// Kernel 2: per-batch MaxSim via MFMA, fragments gathered straight from the
// L2/L3-resident bf16 table (no data staging). One block = one batch.
// ---------------------------------------------------------------------------
__global__ __launch_bounds__(256) void colbert_score_mfma(
    const int* __restrict__ qids, const int* __restrict__ qmask,
    const int* __restrict__ dids, const int* __restrict__ dmask,
    const unsigned short* __restrict__ pebf, float* __restrict__ out) {
  __shared__ int sqid[32];
  __shared__ int sdid[192];
  __shared__ unsigned char smsk[192];
  __shared__ float wmax[4][32];

  const int b    = blockIdx.x;
  const int tid  = threadIdx.x;
  const int lane = tid & 63;
  const int wid  = tid >> 6;
  const int lr   = lane & 15;
  const int kq   = lane >> 4;

  if (tid < 32) sqid[tid] = qids[b * QLEN + tid];
  if (tid < 192) {
    if (tid < DLEN) {
      sdid[tid] = dids[b * DLEN + tid];
      smsk[tid] = (unsigned char)(dmask[b * DLEN + tid] > 0 ? 1 : 0);
    } else {
      sdid[tid] = 0;
      smsk[tid] = 0;
    }
  }
  __syncthreads();

  bf16x8 af[2][4];
#pragma unroll
  for (int mi = 0; mi < 2; ++mi) {
    size_t base = (size_t)sqid[mi * 16 + lr] * EMB + kq * 8;
#pragma unroll
    for (int ks = 0; ks < 4; ++ks)
      af[mi][ks] = *(const bf16x8*)(pebf + base + ks * 32);
  }
  const int n0 = wid * 48;
  bf16x8 bfr[3][4];
#pragma unroll
  for (int ni = 0; ni < 3; ++ni) {
    size_t base = (size_t)sdid[n0 + ni * 16 + lr] * EMB + kq * 8;
#pragma unroll
    for (int ks = 0; ks < 4; ++ks)
      bfr[ni][ks] = *(const bf16x8*)(pebf + base + ks * 32);
  }

  f32x4 acc[2][3];
#pragma unroll
  for (int mi = 0; mi < 2; ++mi)
#pragma unroll
    for (int ni = 0; ni < 3; ++ni) acc[mi][ni] = (f32x4)0.f;

#pragma unroll
  for (int ks = 0; ks < 4; ++ks)
#pragma unroll
    for (int mi = 0; mi < 2; ++mi)
#pragma unroll
      for (int ni = 0; ni < 3; ++ni)
        acc[mi][ni] = __builtin_amdgcn_mfma_f32_16x16x32_bf16(af[mi][ks], bfr[ni][ks], acc[mi][ni], 0, 0, 0);

#pragma unroll
  for (int mi = 0; mi < 2; ++mi) {
#pragma unroll
    for (int j = 0; j < 4; ++j) {
      float m = -3.0e38f;
#pragma unroll
      for (int ni = 0; ni < 3; ++ni) {
        int t = n0 + ni * 16 + lr;
        float s = smsk[t] ? acc[mi][ni][j] : NEGV;
        m = fmaxf(m, s);
      }
#pragma unroll
      for (int x = 1; x < 16; x <<= 1) m = fmaxf(m, __shfl_xor(m, x));
      if (lr == 0) wmax[wid][mi * 16 + kq * 4 + j] = m;
    }
  }
  __syncthreads();

  if (tid < 32) {
    float m = fmaxf(fmaxf(wmax[0][tid], wmax[1][tid]),
                    fmaxf(wmax[2][tid], wmax[3][tid]));
    float s = m * (float)qmask[b * QLEN + tid];
#pragma unroll
    for (int x = 1; x < 32; x <<= 1) s += __shfl_xor(s, x);
    if (tid == 0) out[b] = s;
  }
}

// ---------------------------------------------------------------------------
extern "C" void kernel_launch(void* const* d_in, const int* in_sizes, int n_in,
                              void* d_out, int out_size, void* d_ws, size_t ws_size,
                              hipStream_t stream) {
  const int*   qids  = (const int*)d_in[0];
  const int*   qmask = (const int*)d_in[1];
  const int*   dids  = (const int*)d_in[2];
  const int*   dmask = (const int*)d_in[3];
  const float* emb   = (const float*)d_in[4];
  const float* W     = (const float*)d_in[5];
  const float* bias  = (const float*)d_in[6];
  float*       out   = (float*)d_out;

  char* ws = (char*)d_ws;
  unsigned short* pebf = (unsigned short*)ws;                 // 7,813,632 B
  unsigned short* wfh  = (unsigned short*)(ws + 7813632);     //   196,608 B
  unsigned short* wfl  = (unsigned short*)(ws + 7813632 + 196608);

  prep_wfrag<<<48, 256, 0, stream>>>(W, wfh, wfl);
  colbert_proj_mfma<<<(VOCAB + 31) / 32, 256, 0, stream>>>(emb, wfh, wfl, bias, pebf);
  colbert_score_mfma<<<BATCH, 256, 0, stream>>>(qids, qmask, dids, dmask, pebf, out);
}